// Round 2
// baseline (947.542 us; speedup 1.0000x reference)
//
#include <hip/hip_runtime.h>

// ============================================================================
// Attention_18923625906467 — MI355X (round 9)
//   out = ((x@Wsep^T)@Wmulti^T -> heads -> softmax(QK^T/sqrt(512))V) @ Wres^T
// B=2,S=2048,D=512,H=8.  f32 in/out; bf16 MFMA compute (2%-rel threshold).
//
// R8 profile: attn 485 µs, MfmaUtil 11.7%, VALUBusy 13.9%, occ 23.6%,
// bank-conflict rate unchanged. Per-step (18.2k cyc) dominated by fixed
// costs: 2 barriers + vmcnt drains of 128 KB/CU staged via L1, ~32 serial
// shfl softmax ops. R9: KT=64 keys/step (32 steps), 128 q-rows/block,
// 8 waves/block, grid 256 = 1 block/CU -> staging bytes per key HALVED,
// barrier events per key HALVED. Softmax: sum-reduce deferred to epilogue
// (per-lane partials), max-reduce behind __any(own-m>8) ballot (fires ~once).
// XOR-swizzled Ks/Vs/P for the new 128B-stride rows (else 16-way conflict).
// LDS 148.5 KB/block -> 1 block/CU, 2 waves/SIMD (VGPR-bound, same as R8).
// ============================================================================

typedef __bf16 bf16_t;
typedef __bf16 bf16x4 __attribute__((ext_vector_type(4)));
typedef __bf16 bf16x8 __attribute__((ext_vector_type(8)));
typedef float  f32x4  __attribute__((ext_vector_type(4)));

#define BM 128
#define BN 128
#define BK 64
#define LDK 72   // GEMM LDS row stride (bf16): 144B = 9*16B aligned, 2-way banks

typedef const __attribute__((address_space(1))) void gvoid_t;
typedef __attribute__((address_space(3))) void svoid_t;

__device__ __forceinline__ void async_cp16(const bf16_t* g, bf16_t* l)
{
    __builtin_amdgcn_global_load_lds((gvoid_t*)g, (svoid_t*)l, 16, 0, 0);
}

// ---------------------------------------------------------------------------
__global__ void f32_to_bf16(const float* __restrict__ src, bf16_t* __restrict__ dst, int n4)
{
    const int i = blockIdx.x * 256 + threadIdx.x;
    if (i < n4) {
        const float4 v = ((const float4*)src)[i];
        bf16x4 o;
        o[0] = (bf16_t)v.x; o[1] = (bf16_t)v.y; o[2] = (bf16_t)v.z; o[3] = (bf16_t)v.w;
        ((bf16x4*)dst)[i] = o;
    }
}

// ---------------------------------------------------------------------------
// GEMM: D = A @ W^T + bias.  A:[M,lda], W:[N,ldw] row-major bf16, K inner.
//   C    != nullptr : write bf16 C[row*N+col]
//   Cacc != nullptr : f32 Cacc[row*N+col] = v (accFirst) or += v
//   qk   != nullptr : attention scatter (col = hh*1536 + off, row = bb*2048+ss):
//       off<1024 -> qk[((bb*hmul+hh)*2048+ss)*1024 + off]   (Q:0..511 K:512..1023)
//       else     -> vT[((bb*hmul+hh)*512+(off-1024))*2048 + ss]
// ---------------------------------------------------------------------------
__global__ __launch_bounds__(256, 2)
void gemm_bt(const bf16_t* __restrict__ A, int lda,
             const bf16_t* __restrict__ W, int ldw,
             const float* __restrict__ bias,
             bf16_t* __restrict__ C, float* __restrict__ Cacc, int accFirst,
             int N, int K,
             bf16_t* __restrict__ qk, bf16_t* __restrict__ vT, int hmul)
{
    __shared__ __align__(16) bf16_t As[BM * LDK];
    __shared__ __align__(16) bf16_t Ws[BN * LDK];

    const int tid  = threadIdx.x;
    const int wave = tid >> 6;
    const int lane = tid & 63;
    const int quad = lane >> 4;
    const int l16  = lane & 15;
    const int bm = blockIdx.y * BM;
    const int bn = blockIdx.x * BN;
    const int wm = (wave >> 1) * 64;
    const int wn = (wave & 1) * 64;

    f32x4 acc[4][4] = {};

    const int srow = tid >> 3;
    const int sseg = tid & 7;

    for (int k0 = 0; k0 < K; k0 += BK) {
        #pragma unroll
        for (int it = 0; it < 4; ++it) {
            const int row = it * 32 + srow;
            const int4 va = *(const int4*)(A + (size_t)(bm + row) * lda + k0 + sseg * 8);
            *(int4*)(As + row * LDK + sseg * 8) = va;
            const int4 vw = *(const int4*)(W + (size_t)(bn + row) * ldw + k0 + sseg * 8);
            *(int4*)(Ws + row * LDK + sseg * 8) = vw;
        }
        __syncthreads();
        #pragma unroll
        for (int kk = 0; kk < BK; kk += 32) {
            bf16x8 af[4], wf[4];
            #pragma unroll
            for (int i = 0; i < 4; ++i)
                af[i] = *(const bf16x8*)(As + (wm + i * 16 + l16) * LDK + kk + quad * 8);
            #pragma unroll
            for (int j = 0; j < 4; ++j)
                wf[j] = *(const bf16x8*)(Ws + (wn + j * 16 + l16) * LDK + kk + quad * 8);
            #pragma unroll
            for (int i = 0; i < 4; ++i)
                #pragma unroll
                for (int j = 0; j < 4; ++j)
                    acc[i][j] = __builtin_amdgcn_mfma_f32_16x16x32_bf16(af[i], wf[j], acc[i][j], 0, 0, 0);
        }
        __syncthreads();
    }

    #pragma unroll
    for (int j = 0; j < 4; ++j) {
        const int col = bn + wn + j * 16 + l16;
        const float bv = bias ? bias[col] : 0.f;
        #pragma unroll
        for (int i = 0; i < 4; ++i) {
            const int row0 = bm + wm + i * 16 + quad * 4;
            #pragma unroll
            for (int r = 0; r < 4; ++r) {
                const int row = row0 + r;
                const float v = acc[i][j][r] + bv;
                if (C)
                    C[(size_t)row * N + col] = (bf16_t)v;
                if (Cacc) {
                    const size_t idx = (size_t)row * N + col;
                    Cacc[idx] = accFirst ? v : (Cacc[idx] + v);
                }
                if (qk) {
                    const int hh  = col / 1536;
                    const int off = col - hh * 1536;
                    const int bb  = row >> 11;
                    const int ss  = row & 2047;
                    if (off < 1024)
                        qk[((size_t)((bb * hmul + hh) * 2048 + ss)) * 1024 + off] = (bf16_t)v;
                    else
                        vT[((size_t)((bb * hmul + hh) * 512 + (off - 1024))) * 2048 + ss] = (bf16_t)v;
                }
            }
        }
    }
}

// ---------------------------------------------------------------------------
// Flash attention, round-9 structure.
// Grid nPairs*16 blocks x 512 thr (8 waves, 128 q-rows/block); 1 block/CU.
// KT=64 keys/step, 32 steps.
//   QK: wave w owns q-rows w*16..+15; reads all 64 K-rows from swizzled Ks.
//   softmax: defer-max (__any ballot, THR=8), per-lane l partials (no
//            per-step sum reduce); alphas shared via aLds.
//   PV: wave w -> O[qh*64.. x dw*128..] (qh=w>>2, dw=w&3); V frag reused 4x.
// LDS swizzle (involution, applied on global src at stage + on read):
//   Ks[64][512]: 16B seg s of row r holds global seg s^(r&7)
//   Vs[512][64], P[128][64] (128B rows = 32 banks!): seg s of row r holds
//   global seg s^(r&7) -> every ds_read_b128 phase hits 8 distinct slots.
// Per step: QK, softmax, P write | sync1 (drains V(kt)) | stageK(kt+1),
//   rescale (guarded), PV | sync2 (drains K(kt+1)) | stageV(kt+1).
// ---------------------------------------------------------------------------
__global__ __launch_bounds__(512, 2)
void attn(const bf16_t* __restrict__ qk, const bf16_t* __restrict__ vT,
          bf16_t* __restrict__ aout, int nPairs, int nH,
          int out_stride, int coloff_per_head)
{
    __shared__ __align__(16) bf16_t Ks[64 * 512];    // 64 KB
    __shared__ __align__(16) bf16_t Vs[512 * 64];    // 64 KB
    __shared__ __align__(16) bf16_t Plds[128 * 64];  // 16 KB
    __shared__ float aLds[128];
    __shared__ float lLds[128];

    const int tid  = threadIdx.x;
    const int wave = tid >> 6;
    const int lane = tid & 63;
    const int quad = lane >> 4;
    const int l16  = lane & 15;
    const int qh   = wave >> 2;       // PV q-half  (0..1)
    const int dw   = wave & 3;        // PV d-block (0..3)

    const int bid = blockIdx.x;
    const int p   = bid % nPairs;     // pair (b*nH + h)
    const int qt  = bid / nPairs;     // 0..15

    const bf16_t* qp = qk + ((size_t)(p * 2048 + qt * 128 + wave * 16)) * 1024;
    const bf16_t* kp = qk + ((size_t)(p * 2048)) * 1024 + 512;
    const bf16_t* vp = vT + (size_t)p * 512 * 2048;

    // ---- staging: linear LDS dest (slot*16B = wave-uniform + lane*16B),
    //      XOR-swizzle applied on the global source address ----
    auto stageK = [&](int key0) {
        #pragma unroll
        for (int it = 0; it < 8; ++it) {
            const int slot = it * 512 + tid;
            const int row  = slot >> 6;                  // 0..63
            const int gseg = (slot & 63) ^ (row & 7);
            async_cp16(kp + (size_t)(key0 + row) * 1024 + gseg * 8,
                       Ks + slot * 8);
        }
    };
    auto stageV = [&](int key0) {
        #pragma unroll
        for (int it = 0; it < 8; ++it) {
            const int slot = it * 512 + tid;
            const int row  = slot >> 3;                  // 0..511
            const int gseg = (slot & 7) ^ (row & 7);
            async_cp16(vp + (size_t)row * 2048 + key0 + gseg * 8,
                       Vs + slot * 8);
        }
    };

    // ---- stage tile 0, preload Q fragments (read exactly once) ----
    stageK(0);
    stageV(0);
    bf16x8 qreg[16];
    #pragma unroll
    for (int ks = 0; ks < 16; ++ks)
        qreg[ks] = *(const bf16x8*)(qp + (size_t)l16 * 1024 + ks * 32 + quad * 8);

    f32x4 o[4][8] = {};                   // O[ (qh*64 + rt*16) x (dw*128 + ct*16) ]
    float m_i[4], l_p[4];
    #pragma unroll
    for (int r = 0; r < 4; ++r) { m_i[r] = -10000.f; l_p[r] = 0.f; }

    const float scale = 0.0441941738241592f;  // 1/sqrt(512)
    const int   kx    = l16 & 7;              // read-side swizzle key

    __syncthreads();   // K(0), V(0) resident

    for (int kt = 0; kt < 32; ++kt) {
        // ---- S = Q K^T : own 16 q-rows x 64 keys, K from swizzled LDS ----
        f32x4 s[4] = {};
        __builtin_amdgcn_s_setprio(1);
        #pragma unroll
        for (int ks = 0; ks < 16; ++ks) {
            #pragma unroll
            for (int j = 0; j < 4; ++j) {
                const bf16x8 kf = *(const bf16x8*)(Ks + (j * 16 + l16) * 512
                                                      + (((ks * 4 + quad) ^ kx) * 8));
                s[j] = __builtin_amdgcn_mfma_f32_16x16x32_bf16(qreg[ks], kf, s[j], 0, 0, 0);
            }
        }
        __builtin_amdgcn_s_setprio(0);
        #pragma unroll
        for (int j = 0; j < 4; ++j) s[j] *= scale;

        // ---- defer-max softmax: common path has NO cross-lane ops ----
        float own[4];
        #pragma unroll
        for (int r = 0; r < 4; ++r)
            own[r] = fmaxf(fmaxf(s[0][r], s[1][r]), fmaxf(s[2][r], s[3][r]));
        const float g = fmaxf(fmaxf(own[0] - m_i[0], own[1] - m_i[1]),
                              fmaxf(own[2] - m_i[2], own[3] - m_i[3]));
        float alpha[4] = {1.f, 1.f, 1.f, 1.f};
        if (__any(g > 8.f)) {             // rare: step 0 + genuine max growth
            #pragma unroll
            for (int r = 0; r < 4; ++r) {
                float v = own[r];
                v = fmaxf(v, __shfl_xor(v, 1));
                v = fmaxf(v, __shfl_xor(v, 2));
                v = fmaxf(v, __shfl_xor(v, 4));
                v = fmaxf(v, __shfl_xor(v, 8));
                const float mn = fmaxf(m_i[r], v);
                alpha[r] = __expf(m_i[r] - mn);
                m_i[r] = mn;
                l_p[r] *= alpha[r];
            }
        }
        if (l16 == 0) {
            #pragma unroll
            for (int r = 0; r < 4; ++r)
                aLds[wave * 16 + quad * 4 + r] = alpha[r];
        }

        // ---- P = exp(S - m) -> swizzled LDS; l partial per lane ----
        #pragma unroll
        for (int j = 0; j < 4; ++j)
            #pragma unroll
            for (int r = 0; r < 4; ++r) {
                const float pe = __expf(s[j][r] - m_i[r]);   // bounded by e^8
                l_p[r] += pe;
                const int row = wave * 16 + quad * 4 + r;
                const int sg  = (j * 2 + (l16 >> 3)) ^ (row & 7);
                Plds[row * 64 + sg * 8 + (l16 & 7)] = (bf16_t)pe;
            }

        __syncthreads();   // sync1: V(kt) drained; P/alpha visible; Ks dead

        const int nkey = ((kt + 1) & 31) * 64;   // wrap: last stage is dead data
        stageK(nkey);                            // drained at sync2 (PV window)

        // ---- rescale O by shared alphas (skipped when all 1 — common) ----
        #pragma unroll
        for (int rt = 0; rt < 4; ++rt) {
            const float a0 = aLds[qh * 64 + rt * 16 + quad * 4 + 0];
            const float a1 = aLds[qh * 64 + rt * 16 + quad * 4 + 1];
            const float a2 = aLds[qh * 64 + rt * 16 + quad * 4 + 2];
            const float a3 = aLds[qh * 64 + rt * 16 + quad * 4 + 3];
            if (a0 != 1.f || a1 != 1.f || a2 != 1.f || a3 != 1.f) {
                #pragma unroll
                for (int ct = 0; ct < 8; ++ct) {
                    f32x4 t = o[rt][ct];
                    t[0] *= a0; t[1] *= a1; t[2] *= a2; t[3] *= a3;
                    o[rt][ct] = t;
                }
            }
        }

        // ---- O += P V : wave tile [64q x 128d]; V frag reused 4x ----
        __builtin_amdgcn_s_setprio(1);
        #pragma unroll
        for (int kk = 0; kk < 2; ++kk) {
            bf16x8 pa[4];
            #pragma unroll
            for (int rt = 0; rt < 4; ++rt)
                pa[rt] = *(const bf16x8*)(Plds + (qh * 64 + rt * 16 + l16) * 64
                                               + (((kk * 4 + quad) ^ kx) * 8));
            #pragma unroll
            for (int ct = 0; ct < 8; ++ct) {
                const bf16x8 vf = *(const bf16x8*)(Vs + (dw * 128 + ct * 16 + l16) * 64
                                                      + (((kk * 4 + quad) ^ kx) * 8));
                #pragma unroll
                for (int rt = 0; rt < 4; ++rt)
                    o[rt][ct] = __builtin_amdgcn_mfma_f32_16x16x32_bf16(pa[rt], vf, o[rt][ct], 0, 0, 0);
            }
        }
        __builtin_amdgcn_s_setprio(0);

        __syncthreads();   // sync2: K(kt+1) drained; Vs/P dead

        stageV(nkey);      // drained at next sync1 (QK+softmax window)
    }

    // ---- epilogue: reduce l partials once, share via LDS, write O ----
    #pragma unroll
    for (int r = 0; r < 4; ++r) {
        float t = l_p[r];
        t += __shfl_xor(t, 1);
        t += __shfl_xor(t, 2);
        t += __shfl_xor(t, 4);
        t += __shfl_xor(t, 8);
        if (l16 == 0) lLds[wave * 16 + quad * 4 + r] = t;
    }
    __syncthreads();

    const int b_out  = p / nH;
    const int coloff = (p % nH) * coloff_per_head + dw * 128;
    #pragma unroll
    for (int rt = 0; rt < 4; ++rt) {
        #pragma unroll
        for (int r = 0; r < 4; ++r) {
            const float linv = 1.f / lLds[qh * 64 + rt * 16 + quad * 4 + r];
            const int row = b_out * 2048 + qt * 128 + qh * 64 + rt * 16 + quad * 4 + r;
            #pragma unroll
            for (int ct = 0; ct < 8; ++ct)
                aout[(size_t)row * out_stride + coloff + ct * 16 + l16] =
                    (bf16_t)(o[rt][ct][r] * linv);
        }
    }
}

// ---------------------------------------------------------------------------
extern "C" void kernel_launch(void* const* d_in, const int* in_sizes, int n_in,
                              void* d_out, int out_size, void* d_ws, size_t ws_size,
                              hipStream_t stream)
{
    const float* x       = (const float*)d_in[0];  // [4096, 512]   f32
    const float* W_sep   = (const float*)d_in[1];  // [1536, 512]   f32
    const float* b_sep   = (const float*)d_in[2];  // [1536]        f32
    const float* W_multi = (const float*)d_in[3];  // [12288, 1536] f32
    const float* b_multi = (const float*)d_in[4];  // [12288]       f32
    const float* W_res   = (const float*)d_in[5];  // [512, 4096]   f32
    const float* b_res   = (const float*)d_in[6];  // [512]         f32
    float* out = (float*)d_out;                    // [4096, 512]   f32

    char* ws = (char*)d_ws;
    const dim3 blk(256);
    const dim3 ablk(512);

    if (ws_size >= 160956416ull) {
        // ------------- tier 1: 161 MB, whole-problem dispatches -------------
        bf16_t* wmb = (bf16_t*)(ws);                   // [12288,1536] 37.75 MB
        bf16_t* av  = (bf16_t*)(ws);                   // [4096,4096]  33.55 MB (over wmb, dead)
        bf16_t* xb  = (bf16_t*)(ws +  37748736ull);    // [4096,512]    4.19 MB
        bf16_t* wsb = (bf16_t*)(ws +  41943040ull);    // [1536,512]    1.57 MB
        bf16_t* wrb = (bf16_t*)(ws +  43515904ull);    // [512,4096]    4.19 MB
        bf16_t* h1  = (bf16_t*)(ws +  47710208ull);    // [4096,1536]  12.58 MB
        bf16_t* qk  = (bf16_t*)(ws +  60293120ull);    // [2,8,2048,1024] 67.11 MB
        bf16_t* vT  = (bf16_t*)(ws + 127401984ull);    // [2,8,512,2048]  33.55 MB

        f32_to_bf16<<<dim3( 2048), blk, 0, stream>>>(x,       xb,  2097152 / 4);
        f32_to_bf16<<<dim3(  768), blk, 0, stream>>>(W_sep,   wsb,  786432 / 4);
        f32_to_bf16<<<dim3(18432), blk, 0, stream>>>(W_multi, wmb, 18874368 / 4);
        f32_to_bf16<<<dim3( 2048), blk, 0, stream>>>(W_res,   wrb,  2097152 / 4);

        gemm_bt<<<dim3(12, 32), blk, 0, stream>>>(xb, 512, wsb, 512, b_sep,
                                                  h1, nullptr, 0, 1536, 512,
                                                  nullptr, nullptr, 0);
        gemm_bt<<<dim3(96, 32), blk, 0, stream>>>(h1, 1536, wmb, 1536, b_multi,
                                                  nullptr, nullptr, 0, 12288, 1536,
                                                  qk, vT, 8);
        attn<<<dim3(256), ablk, 0, stream>>>(qk, vT, av, 16, 8, 4096, 512);
        gemm_bt<<<dim3(4, 32), blk, 0, stream>>>(av, 4096, wrb, 4096, b_res,
                                                 nullptr, out, 1, 512, 4096,
                                                 nullptr, nullptr, 0);
    } else if (ws_size >= 39845888ull) {
        // ------------- tier 2: 39.8 MB, per-head streaming -------------
        bf16_t* h1    = (bf16_t*)(ws);                 // [4096,1536]  12.58 MB
        bf16_t* xb    = (bf16_t*)(ws + 12582912ull);   // [4096,512]    4.19 MB (dead after GEMM1)
        bf16_t* av_h  = (bf16_t*)(ws + 12582912ull);   //   reuse: [4096,512] bf16
        bf16_t* wsb   = (bf16_t*)(ws + 16777216ull);   // [1536,512]    1.57 MB
        bf16_t* wrb   = (bf16_t*)(ws + 18350080ull);   // [512,4096]    4.19 MB
        bf16_t* wmb_h = (bf16_t*)(ws + 22544384ull);   // [1536,1536]   4.72 MB
        bf16_t* qk_h  = (bf16_t*)(ws + 27262976ull);   // [2,2048,1024] 8.39 MB
        bf16_t* vT_h  = (bf16_t*)(ws + 35651584ull);   // [2,512,2048]  4.19 MB

        f32_to_bf16<<<dim3(2048), blk, 0, stream>>>(x,     xb,  2097152 / 4);
        f32_to_bf16<<<dim3( 768), blk, 0, stream>>>(W_sep, wsb,  786432 / 4);
        f32_to_bf16<<<dim3(2048), blk, 0, stream>>>(W_res, wrb,  2097152 / 4);

        gemm_bt<<<dim3(12, 32), blk, 0, stream>>>(xb, 512, wsb, 512, b_sep,
                                                  h1, nullptr, 0, 1536, 512,
                                                  nullptr, nullptr, 0);
        for (int h = 0; h < 8; ++h) {
            f32_to_bf16<<<dim3(2304), blk, 0, stream>>>(W_multi + (size_t)h * 1536 * 1536,
                                                        wmb_h, 2359296 / 4);
            gemm_bt<<<dim3(12, 32), blk, 0, stream>>>(h1, 1536, wmb_h, 1536,
                    b_multi + h * 1536, nullptr, nullptr, 0, 1536, 1536,
                    qk_h, vT_h, 1);
            attn<<<dim3(32), ablk, 0, stream>>>(qk_h, vT_h, av_h, 2, 1, 512, 0);
            gemm_bt<<<dim3(4, 32), blk, 0, stream>>>(av_h, 512, wrb + h * 512, 4096,
                    (h == 0) ? b_res : nullptr, nullptr, out, (h == 0) ? 1 : 0,
                    512, 512, nullptr, nullptr, 0);
        }
    } else {
        // ------------- tier 3: exactly 32 MiB, per-(batch,head) -------------
        bf16_t* h1    = (bf16_t*)(ws);                 // [4096,1536]  12.58 MB
        bf16_t* xb    = (bf16_t*)(ws + 12582912ull);   // [4096,512]    4.19 MB (dead after GEMM1)
        bf16_t* av_bh = (bf16_t*)(ws + 12582912ull);   //   reuse: [2048,512] bf16
        bf16_t* wsb   = (bf16_t*)(ws + 16777216ull);   // [1536,512]    1.57 MB
        bf16_t* wrb   = (bf16_t*)(ws + 18350080ull);   // [512,4096]    4.19 MB
        bf16_t* wmb_h = (bf16_t*)(ws + 22544384ull);   // [1536,1536]   4.72 MB
        bf16_t* qk_bh = (bf16_t*)(ws + 27262976ull);   // [2048,1024]   4.19 MB
        bf16_t* vT_bh = (bf16_t*)(ws + 31457280ull);   // [512,2048]    2.10 MB

        f32_to_bf16<<<dim3(2048), blk, 0, stream>>>(x,     xb,  2097152 / 4);
        f32_to_bf16<<<dim3( 768), blk, 0, stream>>>(W_sep, wsb,  786432 / 4);
        f32_to_bf16<<<dim3(2048), blk, 0, stream>>>(W_res, wrb,  2097152 / 4);

        gemm_bt<<<dim3(12, 32), blk, 0, stream>>>(xb, 512, wsb, 512, b_sep,
                                                  h1, nullptr, 0, 1536, 512,
                                                  nullptr, nullptr, 0);
        for (int h = 0; h < 8; ++h) {
            f32_to_bf16<<<dim3(2304), blk, 0, stream>>>(W_multi + (size_t)h * 1536 * 1536,
                                                        wmb_h, 2359296 / 4);
            for (int b = 0; b < 2; ++b) {
                gemm_bt<<<dim3(12, 16), blk, 0, stream>>>(h1 + (size_t)b * 2048 * 1536, 1536,
                        wmb_h, 1536, b_multi + h * 1536,
                        nullptr, nullptr, 0, 1536, 1536, qk_bh, vT_bh, 1);
                attn<<<dim3(16), ablk, 0, stream>>>(qk_bh, vT_bh, av_bh, 1, 1, 512, 0);
                gemm_bt<<<dim3(4, 16), blk, 0, stream>>>(av_bh, 512, wrb + h * 512, 4096,
                        (h == 0) ? b_res : nullptr, nullptr, out + (size_t)b * 2048 * 512,
                        (h == 0) ? 1 : 0, 512, 512, nullptr, nullptr, 0);
            }
        }
    }
}

// Round 3
// 731.153 us; speedup vs baseline: 1.2960x; 1.2960x over previous
//
#include <hip/hip_runtime.h>

// ============================================================================
// Attention_18923625906467 — MI355X (round 10)
//   out = ((x@Wsep^T)@Wmulti^T -> heads -> softmax(QK^T/sqrt(512))V) @ Wres^T
// B=2,S=2048,D=512,H=8.  f32 in/out; bf16 MFMA compute (2%-rel threshold).
//
// R9 profile: attn 515 µs, MfmaUtil 10.7 (= % of MFMA peak), VALU 7.4,
// FETCH 555 MB. Per-unit efficiency identical to R8 -> the stall is the
// per-step vmcnt(0) drains at __syncthreads (2-phase regime, m233/m218).
// R10: KT=32, DOUBLE-buffered K+V (137 KB LDS, 1 block/CU). stage(t+1)
// issued at step top (full-step landing window); mid-step barrier is
// lgkmcnt(0)+s_barrier with NO vmcnt drain (stage loads stay in flight
// across it); single vmcnt(0) after PV. q=128/block kept (K re-read 16x).
// ============================================================================

typedef __bf16 bf16_t;
typedef __bf16 bf16x4 __attribute__((ext_vector_type(4)));
typedef __bf16 bf16x8 __attribute__((ext_vector_type(8)));
typedef float  f32x4  __attribute__((ext_vector_type(4)));

#define BM 128
#define BN 128
#define BK 64
#define LDK 72   // GEMM LDS row stride (bf16): 144B = 9*16B aligned, 2-way banks

typedef const __attribute__((address_space(1))) void gvoid_t;
typedef __attribute__((address_space(3))) void svoid_t;

__device__ __forceinline__ void async_cp16(const bf16_t* g, bf16_t* l)
{
    __builtin_amdgcn_global_load_lds((gvoid_t*)g, (svoid_t*)l, 16, 0, 0);
}

__device__ __forceinline__ void bar_lgkm()
{
    asm volatile("s_waitcnt lgkmcnt(0)" ::: "memory");
    __builtin_amdgcn_s_barrier();
}

__device__ __forceinline__ void wait_vm0()
{
    asm volatile("s_waitcnt vmcnt(0)" ::: "memory");
}

// ---------------------------------------------------------------------------
__global__ void f32_to_bf16(const float* __restrict__ src, bf16_t* __restrict__ dst, int n4)
{
    const int i = blockIdx.x * 256 + threadIdx.x;
    if (i < n4) {
        const float4 v = ((const float4*)src)[i];
        bf16x4 o;
        o[0] = (bf16_t)v.x; o[1] = (bf16_t)v.y; o[2] = (bf16_t)v.z; o[3] = (bf16_t)v.w;
        ((bf16x4*)dst)[i] = o;
    }
}

// ---------------------------------------------------------------------------
// GEMM: D = A @ W^T + bias.  A:[M,lda], W:[N,ldw] row-major bf16, K inner.
//   C    != nullptr : write bf16 C[row*N+col]
//   Cacc != nullptr : f32 Cacc[row*N+col] = v (accFirst) or += v
//   qk   != nullptr : attention scatter (col = hh*1536 + off, row = bb*2048+ss):
//       off<1024 -> qk[((bb*hmul+hh)*2048+ss)*1024 + off]   (Q:0..511 K:512..1023)
//       else     -> vT[((bb*hmul+hh)*512+(off-1024))*2048 + ss]
// ---------------------------------------------------------------------------
__global__ __launch_bounds__(256, 2)
void gemm_bt(const bf16_t* __restrict__ A, int lda,
             const bf16_t* __restrict__ W, int ldw,
             const float* __restrict__ bias,
             bf16_t* __restrict__ C, float* __restrict__ Cacc, int accFirst,
             int N, int K,
             bf16_t* __restrict__ qk, bf16_t* __restrict__ vT, int hmul)
{
    __shared__ __align__(16) bf16_t As[BM * LDK];
    __shared__ __align__(16) bf16_t Ws[BN * LDK];

    const int tid  = threadIdx.x;
    const int wave = tid >> 6;
    const int lane = tid & 63;
    const int quad = lane >> 4;
    const int l16  = lane & 15;
    const int bm = blockIdx.y * BM;
    const int bn = blockIdx.x * BN;
    const int wm = (wave >> 1) * 64;
    const int wn = (wave & 1) * 64;

    f32x4 acc[4][4] = {};

    const int srow = tid >> 3;
    const int sseg = tid & 7;

    for (int k0 = 0; k0 < K; k0 += BK) {
        #pragma unroll
        for (int it = 0; it < 4; ++it) {
            const int row = it * 32 + srow;
            const int4 va = *(const int4*)(A + (size_t)(bm + row) * lda + k0 + sseg * 8);
            *(int4*)(As + row * LDK + sseg * 8) = va;
            const int4 vw = *(const int4*)(W + (size_t)(bn + row) * ldw + k0 + sseg * 8);
            *(int4*)(Ws + row * LDK + sseg * 8) = vw;
        }
        __syncthreads();
        #pragma unroll
        for (int kk = 0; kk < BK; kk += 32) {
            bf16x8 af[4], wf[4];
            #pragma unroll
            for (int i = 0; i < 4; ++i)
                af[i] = *(const bf16x8*)(As + (wm + i * 16 + l16) * LDK + kk + quad * 8);
            #pragma unroll
            for (int j = 0; j < 4; ++j)
                wf[j] = *(const bf16x8*)(Ws + (wn + j * 16 + l16) * LDK + kk + quad * 8);
            #pragma unroll
            for (int i = 0; i < 4; ++i)
                #pragma unroll
                for (int j = 0; j < 4; ++j)
                    acc[i][j] = __builtin_amdgcn_mfma_f32_16x16x32_bf16(af[i], wf[j], acc[i][j], 0, 0, 0);
        }
        __syncthreads();
    }

    #pragma unroll
    for (int j = 0; j < 4; ++j) {
        const int col = bn + wn + j * 16 + l16;
        const float bv = bias ? bias[col] : 0.f;
        #pragma unroll
        for (int i = 0; i < 4; ++i) {
            const int row0 = bm + wm + i * 16 + quad * 4;
            #pragma unroll
            for (int r = 0; r < 4; ++r) {
                const int row = row0 + r;
                const float v = acc[i][j][r] + bv;
                if (C)
                    C[(size_t)row * N + col] = (bf16_t)v;
                if (Cacc) {
                    const size_t idx = (size_t)row * N + col;
                    Cacc[idx] = accFirst ? v : (Cacc[idx] + v);
                }
                if (qk) {
                    const int hh  = col / 1536;
                    const int off = col - hh * 1536;
                    const int bb  = row >> 11;
                    const int ss  = row & 2047;
                    if (off < 1024)
                        qk[((size_t)((bb * hmul + hh) * 2048 + ss)) * 1024 + off] = (bf16_t)v;
                    else
                        vT[((size_t)((bb * hmul + hh) * 512 + (off - 1024))) * 2048 + ss] = (bf16_t)v;
                }
            }
        }
    }
}

// ---------------------------------------------------------------------------
// Flash attention, round-10 structure.
// Grid nPairs*16 blocks x 512 thr (8 waves, 128 q-rows/block); 1 block/CU.
// KT=32 keys/step, 64 steps; K and V double-buffered in LDS.
// Per step t (buf b = t&1):
//   issue stage(t+1) -> buf b^1   [freed by Bend(t-1); full-step window]
//   QK from Ks[b]; softmax (defer-max); P+alpha -> LDS
//   B1: lgkmcnt(0)+s_barrier      [NO vmcnt drain: stage loads fly across]
//   rescale (guarded); PV from Vs[b]+Plds
//   vmcnt(0)                      [tile t+1 landed; window already closed]
//   Bend: lgkmcnt(0)+s_barrier
// Swizzles (involution on global src at stage + on read index):
//   Ks[32][512]: seg s of row r holds global seg s^(r&7)
//   Vs[512][32], Plds[128][32]: seg s of row r holds global seg s^(r&3)
// ---------------------------------------------------------------------------
__global__ __launch_bounds__(512, 2)
void attn(const bf16_t* __restrict__ qk, const bf16_t* __restrict__ vT,
          bf16_t* __restrict__ aout, int nPairs, int nH,
          int out_stride, int coloff_per_head)
{
    __shared__ __align__(16) bf16_t Ks[2 * 32 * 512];   // 64 KB
    __shared__ __align__(16) bf16_t Vs[2 * 512 * 32];   // 64 KB
    __shared__ __align__(16) bf16_t Plds[128 * 32];     //  8 KB
    __shared__ float aLds[128];
    __shared__ float lLds[128];

    const int tid  = threadIdx.x;
    const int wave = tid >> 6;
    const int lane = tid & 63;
    const int quad = lane >> 4;
    const int l16  = lane & 15;
    const int qh   = wave >> 2;       // PV q-half  (0..1)
    const int dw   = wave & 3;        // PV d-block (0..3)

    const int bid = blockIdx.x;
    const int p   = bid % nPairs;     // pair (b*nH + h)
    const int qt  = bid / nPairs;     // 0..15

    const bf16_t* qp = qk + ((size_t)(p * 2048 + qt * 128 + wave * 16)) * 1024;
    const bf16_t* kp = qk + ((size_t)(p * 2048)) * 1024 + 512;
    const bf16_t* vp = vT + (size_t)p * 512 * 2048;

    // ---- staging: linear LDS dest, XOR-swizzle on the global source ----
    auto stageK = [&](int bsel, int key0) {
        bf16_t* dst = Ks + bsel * (32 * 512);
        #pragma unroll
        for (int it = 0; it < 4; ++it) {
            const int slot = it * 512 + tid;
            const int row  = slot >> 6;                  // 0..31
            const int gseg = (slot & 63) ^ (row & 7);
            async_cp16(kp + (size_t)(key0 + row) * 1024 + gseg * 8,
                       dst + slot * 8);
        }
    };
    auto stageV = [&](int bsel, int key0) {
        bf16_t* dst = Vs + bsel * (512 * 32);
        #pragma unroll
        for (int it = 0; it < 4; ++it) {
            const int slot = it * 512 + tid;
            const int row  = slot >> 2;                  // 0..511
            const int gseg = (slot & 3) ^ (row & 3);
            async_cp16(vp + (size_t)row * 2048 + key0 + gseg * 8,
                       dst + slot * 8);
        }
    };

    // ---- stage tile 0, preload Q fragments (read exactly once) ----
    stageK(0, 0);
    stageV(0, 0);
    bf16x8 qreg[16];
    #pragma unroll
    for (int ks = 0; ks < 16; ++ks)
        qreg[ks] = *(const bf16x8*)(qp + (size_t)l16 * 1024 + ks * 32 + quad * 8);

    f32x4 o[4][8] = {};                   // O[ (qh*64 + rt*16) x (dw*128 + ct*16) ]
    float m_i[4], l_p[4];
    #pragma unroll
    for (int r = 0; r < 4; ++r) { m_i[r] = -10000.f; l_p[r] = 0.f; }

    const float scale = 0.0441941738241592f;  // 1/sqrt(512)
    const int   kx8   = l16 & 7;              // Ks read swizzle key
    const int   kx4   = l16 & 3;              // Vs/P read swizzle key

    __syncthreads();   // drains vmcnt(0): K(0), V(0) resident

    for (int kt = 0; kt < 64; ++kt) {
        const int b = kt & 1;
        const bf16_t* Kb = Ks + b * (32 * 512);
        const bf16_t* Vb = Vs + b * (512 * 32);

        // ---- prefetch tile t+1 into the other buffer (full-step window) ----
        if (kt + 1 < 64) {
            stageK(b ^ 1, (kt + 1) * 32);
            stageV(b ^ 1, (kt + 1) * 32);
        }

        // ---- S = Q K^T : own 16 q-rows x 32 keys, K from swizzled LDS ----
        f32x4 s[2] = {};
        __builtin_amdgcn_s_setprio(1);
        #pragma unroll
        for (int ks = 0; ks < 16; ++ks) {
            #pragma unroll
            for (int j = 0; j < 2; ++j) {
                const bf16x8 kf = *(const bf16x8*)(Kb + (j * 16 + l16) * 512
                                                      + (((ks * 4 + quad) ^ kx8) * 8));
                s[j] = __builtin_amdgcn_mfma_f32_16x16x32_bf16(qreg[ks], kf, s[j], 0, 0, 0);
            }
        }
        __builtin_amdgcn_s_setprio(0);
        s[0] *= scale; s[1] *= scale;

        // ---- defer-max softmax: common path has NO cross-lane ops ----
        float own[4];
        #pragma unroll
        for (int r = 0; r < 4; ++r)
            own[r] = fmaxf(s[0][r], s[1][r]);
        const float g = fmaxf(fmaxf(own[0] - m_i[0], own[1] - m_i[1]),
                              fmaxf(own[2] - m_i[2], own[3] - m_i[3]));
        float alpha[4] = {1.f, 1.f, 1.f, 1.f};
        if (__any(g > 8.f)) {             // rare: step 0 + genuine max growth
            #pragma unroll
            for (int r = 0; r < 4; ++r) {
                float v = own[r];
                v = fmaxf(v, __shfl_xor(v, 1));
                v = fmaxf(v, __shfl_xor(v, 2));
                v = fmaxf(v, __shfl_xor(v, 4));
                v = fmaxf(v, __shfl_xor(v, 8));
                const float mn = fmaxf(m_i[r], v);
                alpha[r] = __expf(m_i[r] - mn);
                m_i[r] = mn;
                l_p[r] *= alpha[r];
            }
        }
        if (l16 == 0) {
            #pragma unroll
            for (int r = 0; r < 4; ++r)
                aLds[wave * 16 + quad * 4 + r] = alpha[r];
        }

        // ---- P = exp(S - m) -> swizzled LDS; l partial per lane ----
        #pragma unroll
        for (int j = 0; j < 2; ++j)
            #pragma unroll
            for (int r = 0; r < 4; ++r) {
                const float pe = __expf(s[j][r] - m_i[r]);   // bounded by e^8
                l_p[r] += pe;
                const int row = wave * 16 + quad * 4 + r;
                const int sg  = (j * 2 + (l16 >> 3)) ^ (row & 3);
                Plds[row * 32 + sg * 8 + (l16 & 7)] = (bf16_t)pe;
            }

        bar_lgkm();        // B1: P/alpha visible. NO vmcnt drain.

        // ---- rescale O by shared alphas (skipped when all 1 — common) ----
        #pragma unroll
        for (int rt = 0; rt < 4; ++rt) {
            const float a0 = aLds[qh * 64 + rt * 16 + quad * 4 + 0];
            const float a1 = aLds[qh * 64 + rt * 16 + quad * 4 + 1];
            const float a2 = aLds[qh * 64 + rt * 16 + quad * 4 + 2];
            const float a3 = aLds[qh * 64 + rt * 16 + quad * 4 + 3];
            if (a0 != 1.f || a1 != 1.f || a2 != 1.f || a3 != 1.f) {
                #pragma unroll
                for (int ct = 0; ct < 8; ++ct) {
                    f32x4 t = o[rt][ct];
                    t[0] *= a0; t[1] *= a1; t[2] *= a2; t[3] *= a3;
                    o[rt][ct] = t;
                }
            }
        }

        // ---- O += P V : wave tile [64q x 128d] ----
        __builtin_amdgcn_s_setprio(1);
        bf16x8 pa[4];
        #pragma unroll
        for (int rt = 0; rt < 4; ++rt)
            pa[rt] = *(const bf16x8*)(Plds + (qh * 64 + rt * 16 + l16) * 32
                                           + ((quad ^ kx4) * 8));
        #pragma unroll
        for (int ct = 0; ct < 8; ++ct) {
            const bf16x8 vf = *(const bf16x8*)(Vb + (dw * 128 + ct * 16 + l16) * 32
                                                  + ((quad ^ kx4) * 8));
            #pragma unroll
            for (int rt = 0; rt < 4; ++rt)
                o[rt][ct] = __builtin_amdgcn_mfma_f32_16x16x32_bf16(pa[rt], vf, o[rt][ct], 0, 0, 0);
        }
        __builtin_amdgcn_s_setprio(0);

        wait_vm0();        // tile t+1 fills landed (issued at step top)
        bar_lgkm();        // Bend: buffers b^1 ready for all; b free to restage
    }

    // ---- epilogue: reduce l partials once, share via LDS, write O ----
    #pragma unroll
    for (int r = 0; r < 4; ++r) {
        float t = l_p[r];
        t += __shfl_xor(t, 1);
        t += __shfl_xor(t, 2);
        t += __shfl_xor(t, 4);
        t += __shfl_xor(t, 8);
        if (l16 == 0) lLds[wave * 16 + quad * 4 + r] = t;
    }
    __syncthreads();

    const int b_out  = p / nH;
    const int coloff = (p % nH) * coloff_per_head + dw * 128;
    #pragma unroll
    for (int rt = 0; rt < 4; ++rt) {
        #pragma unroll
        for (int r = 0; r < 4; ++r) {
            const float linv = 1.f / lLds[qh * 64 + rt * 16 + quad * 4 + r];
            const int row = b_out * 2048 + qt * 128 + qh * 64 + rt * 16 + quad * 4 + r;
            #pragma unroll
            for (int ct = 0; ct < 8; ++ct)
                aout[(size_t)row * out_stride + coloff + ct * 16 + l16] =
                    (bf16_t)(o[rt][ct][r] * linv);
        }
    }
}

// ---------------------------------------------------------------------------
extern "C" void kernel_launch(void* const* d_in, const int* in_sizes, int n_in,
                              void* d_out, int out_size, void* d_ws, size_t ws_size,
                              hipStream_t stream)
{
    const float* x       = (const float*)d_in[0];  // [4096, 512]   f32
    const float* W_sep   = (const float*)d_in[1];  // [1536, 512]   f32
    const float* b_sep   = (const float*)d_in[2];  // [1536]        f32
    const float* W_multi = (const float*)d_in[3];  // [12288, 1536] f32
    const float* b_multi = (const float*)d_in[4];  // [12288]       f32
    const float* W_res   = (const float*)d_in[5];  // [512, 4096]   f32
    const float* b_res   = (const float*)d_in[6];  // [512]         f32
    float* out = (float*)d_out;                    // [4096, 512]   f32

    char* ws = (char*)d_ws;
    const dim3 blk(256);
    const dim3 ablk(512);

    if (ws_size >= 160956416ull) {
        // ------------- tier 1: 161 MB, whole-problem dispatches -------------
        bf16_t* wmb = (bf16_t*)(ws);                   // [12288,1536] 37.75 MB
        bf16_t* av  = (bf16_t*)(ws);                   // [4096,4096]  33.55 MB (over wmb, dead)
        bf16_t* xb  = (bf16_t*)(ws +  37748736ull);    // [4096,512]    4.19 MB
        bf16_t* wsb = (bf16_t*)(ws +  41943040ull);    // [1536,512]    1.57 MB
        bf16_t* wrb = (bf16_t*)(ws +  43515904ull);    // [512,4096]    4.19 MB
        bf16_t* h1  = (bf16_t*)(ws +  47710208ull);    // [4096,1536]  12.58 MB
        bf16_t* qk  = (bf16_t*)(ws +  60293120ull);    // [2,8,2048,1024] 67.11 MB
        bf16_t* vT  = (bf16_t*)(ws + 127401984ull);    // [2,8,512,2048]  33.55 MB

        f32_to_bf16<<<dim3( 2048), blk, 0, stream>>>(x,       xb,  2097152 / 4);
        f32_to_bf16<<<dim3(  768), blk, 0, stream>>>(W_sep,   wsb,  786432 / 4);
        f32_to_bf16<<<dim3(18432), blk, 0, stream>>>(W_multi, wmb, 18874368 / 4);
        f32_to_bf16<<<dim3( 2048), blk, 0, stream>>>(W_res,   wrb,  2097152 / 4);

        gemm_bt<<<dim3(12, 32), blk, 0, stream>>>(xb, 512, wsb, 512, b_sep,
                                                  h1, nullptr, 0, 1536, 512,
                                                  nullptr, nullptr, 0);
        gemm_bt<<<dim3(96, 32), blk, 0, stream>>>(h1, 1536, wmb, 1536, b_multi,
                                                  nullptr, nullptr, 0, 12288, 1536,
                                                  qk, vT, 8);
        attn<<<dim3(256), ablk, 0, stream>>>(qk, vT, av, 16, 8, 4096, 512);
        gemm_bt<<<dim3(4, 32), blk, 0, stream>>>(av, 4096, wrb, 4096, b_res,
                                                 nullptr, out, 1, 512, 4096,
                                                 nullptr, nullptr, 0);
    } else if (ws_size >= 39845888ull) {
        // ------------- tier 2: 39.8 MB, per-head streaming -------------
        bf16_t* h1    = (bf16_t*)(ws);                 // [4096,1536]  12.58 MB
        bf16_t* xb    = (bf16_t*)(ws + 12582912ull);   // [4096,512]    4.19 MB (dead after GEMM1)
        bf16_t* av_h  = (bf16_t*)(ws + 12582912ull);   //   reuse: [4096,512] bf16
        bf16_t* wsb   = (bf16_t*)(ws + 16777216ull);   // [1536,512]    1.57 MB
        bf16_t* wrb   = (bf16_t*)(ws + 18350080ull);   // [512,4096]    4.19 MB
        bf16_t* wmb_h = (bf16_t*)(ws + 22544384ull);   // [1536,1536]   4.72 MB
        bf16_t* qk_h  = (bf16_t*)(ws + 27262976ull);   // [2,2048,1024] 8.39 MB
        bf16_t* vT_h  = (bf16_t*)(ws + 35651584ull);   // [2,512,2048]  4.19 MB

        f32_to_bf16<<<dim3(2048), blk, 0, stream>>>(x,     xb,  2097152 / 4);
        f32_to_bf16<<<dim3( 768), blk, 0, stream>>>(W_sep, wsb,  786432 / 4);
        f32_to_bf16<<<dim3(2048), blk, 0, stream>>>(W_res, wrb,  2097152 / 4);

        gemm_bt<<<dim3(12, 32), blk, 0, stream>>>(xb, 512, wsb, 512, b_sep,
                                                  h1, nullptr, 0, 1536, 512,
                                                  nullptr, nullptr, 0);
        for (int h = 0; h < 8; ++h) {
            f32_to_bf16<<<dim3(2304), blk, 0, stream>>>(W_multi + (size_t)h * 1536 * 1536,
                                                        wmb_h, 2359296 / 4);
            gemm_bt<<<dim3(12, 32), blk, 0, stream>>>(h1, 1536, wmb_h, 1536,
                    b_multi + h * 1536, nullptr, nullptr, 0, 1536, 1536,
                    qk_h, vT_h, 1);
            attn<<<dim3(32), ablk, 0, stream>>>(qk_h, vT_h, av_h, 2, 1, 512, 0);
            gemm_bt<<<dim3(4, 32), blk, 0, stream>>>(av_h, 512, wrb + h * 512, 4096,
                    (h == 0) ? b_res : nullptr, nullptr, out, (h == 0) ? 1 : 0,
                    512, 512, nullptr, nullptr, 0);
        }
    } else {
        // ------------- tier 3: exactly 32 MiB, per-(batch,head) -------------
        bf16_t* h1    = (bf16_t*)(ws);                 // [4096,1536]  12.58 MB
        bf16_t* xb    = (bf16_t*)(ws + 12582912ull);   // [4096,512]    4.19 MB (dead after GEMM1)
        bf16_t* av_bh = (bf16_t*)(ws + 12582912ull);   //   reuse: [2048,512] bf16
        bf16_t* wsb   = (bf16_t*)(ws + 16777216ull);   // [1536,512]    1.57 MB
        bf16_t* wrb   = (bf16_t*)(ws + 18350080ull);   // [512,4096]    4.19 MB
        bf16_t* wmb_h = (bf16_t*)(ws + 22544384ull);   // [1536,1536]   4.72 MB
        bf16_t* qk_bh = (bf16_t*)(ws + 27262976ull);   // [2048,1024]   4.19 MB
        bf16_t* vT_bh = (bf16_t*)(ws + 31457280ull);   // [512,2048]    2.10 MB

        f32_to_bf16<<<dim3(2048), blk, 0, stream>>>(x,     xb,  2097152 / 4);
        f32_to_bf16<<<dim3( 768), blk, 0, stream>>>(W_sep, wsb,  786432 / 4);
        f32_to_bf16<<<dim3(2048), blk, 0, stream>>>(W_res, wrb,  2097152 / 4);

        gemm_bt<<<dim3(12, 32), blk, 0, stream>>>(xb, 512, wsb, 512, b_sep,
                                                  h1, nullptr, 0, 1536, 512,
                                                  nullptr, nullptr, 0);
        for (int h = 0; h < 8; ++h) {
            f32_to_bf16<<<dim3(2304), blk, 0, stream>>>(W_multi + (size_t)h * 1536 * 1536,
                                                        wmb_h, 2359296 / 4);
            for (int b = 0; b < 2; ++b) {
                gemm_bt<<<dim3(12, 16), blk, 0, stream>>>(h1 + (size_t)b * 2048 * 1536, 1536,
                        wmb_h, 1536, b_multi + h * 1536,
                        nullptr, nullptr, 0, 1536, 1536, qk_bh, vT_bh, 1);
                attn<<<dim3(16), ablk, 0, stream>>>(qk_bh, vT_bh, av_bh, 1, 1, 512, 0);
                gemm_bt<<<dim3(4, 16), blk, 0, stream>>>(av_bh, 512, wrb + h * 512, 4096,
                        (h == 0) ? b_res : nullptr, nullptr, out + (size_t)b * 2048 * 512,
                        (h == 0) ? 1 : 0, 512, 512, nullptr, nullptr, 0);
            }
        }
    }
}